// Round 3
// baseline (1195.625 us; speedup 1.0000x reference)
//
#include <hip/hip_runtime.h>
#include <hip/hip_bf16.h>
#include <stdint.h>

// Problem constants
#define B_    8
#define MD    1024   // MODEL_DIM
#define HD    2048   // HIGH_DIM
#define T_    4096
#define KEEP_ 64
#define CAP   96     // per-column nnz capacity (mean 32; P(>96) ~ 1e-18)
#define BANDW 5e-3f  // band half-width >= 2*(fp16 GEMM err 1.4e-3 + fp16 store err 0.5e-3)
#define AMB   2e-6   // refined-cut ambiguity margin -> exact fp64 fallback
#define NCAND 512    // candidate list capacity for threshold top-k

typedef __attribute__((ext_vector_type(8))) short short8;
typedef __attribute__((ext_vector_type(4))) float f32x4;
typedef __attribute__((ext_vector_type(8))) _Float16 half8;

// async global->LDS, 16B per lane (wave-uniform LDS base + lane*16)
__device__ __forceinline__ void gload_lds16(const void* g, void* l) {
    __builtin_amdgcn_global_load_lds(
        (const __attribute__((address_space(1))) uint32_t*)g,
        (__attribute__((address_space(3))) uint32_t*)l, 16, 0, 0);
}

__device__ __forceinline__ short f2h(float a) {
    _Float16 h = (_Float16)a;
    short s;
    __builtin_memcpy(&s, &h, 2);
    return s;
}

__device__ __forceinline__ float h2f(short s) {
    _Float16 h;
    __builtin_memcpy(&h, &s, 2);
    return (float)h;
}

// split f32 into fp16 hi + fp16 lo (hi+lo reconstructs to ~2^-22 relative)
__device__ __forceinline__ void split1h(float a, short& h, short& l) {
    _Float16 hh = (_Float16)a;
    float r = a - (float)hh;   // exact (Sterbenz)
    h = f2h(a);
    l = f2h(r);
    (void)hh;
}

__device__ __forceinline__ uint32_t sortable(float f) {
    uint32_t u = __float_as_uint(f);
    return (u & 0x80000000u) ? ~u : (u | 0x80000000u);
}

// ---------------------------------------------------------------------------
// Kernel 1: transpose W_c [MD][HD] f32 -> W_cT [HD][MD] bf16 (L2-resident 4MB)
// ---------------------------------------------------------------------------
__global__ void k_transpose_wc(const float* __restrict__ Wc,
                               __hip_bfloat16* __restrict__ WcT) {
    __shared__ float s[32][33];
    const int d0 = blockIdx.x * 32;
    const int m0 = blockIdx.y * 32;
    const int tx = threadIdx.x;   // 0..31
    const int ty = threadIdx.y;   // 0..7
    #pragma unroll
    for (int k = 0; k < 4; k++)
        s[ty + k * 8][tx] = Wc[(size_t)(m0 + ty + k * 8) * HD + d0 + tx];
    __syncthreads();
    #pragma unroll
    for (int k = 0; k < 4; k++)
        WcT[(size_t)(d0 + ty + k * 8) * MD + m0 + tx] =
            __float2bfloat16(s[tx][ty + k * 8]);
}

// ---------------------------------------------------------------------------
// Kernel 1b: round We [HD][MD] f32 -> fp16 (elementwise; single array)
// ---------------------------------------------------------------------------
__global__ void k_round_we(const float* __restrict__ We,
                           short* __restrict__ hi) {
    const int i = (blockIdx.x * 256 + threadIdx.x) * 4;
    float4 v = *(const float4*)&We[i];
    short4 h;
    h.x = f2h(v.x);
    h.y = f2h(v.y);
    h.z = f2h(v.z);
    h.w = f2h(v.w);
    *(short4*)&hi[i] = h;
}

// ---------------------------------------------------------------------------
// Kernel 1c: transpose+split x [B][MD][T] f32 -> xT hi/lo [B][T][MD] fp16.
// hi feeds the 1-pass GEMM; hi+lo reconstruct x to 2^-22 for refinement.
// ---------------------------------------------------------------------------
__global__ void k_split_x(const float* __restrict__ x,
                          short* __restrict__ xTh, short* __restrict__ xTl) {
    __shared__ float s[32][33];   // [c_local][t_local]
    const int t0 = blockIdx.x * 32;
    const int c0 = blockIdx.y * 32;
    const int b  = blockIdx.z;
    const int tx = threadIdx.x;   // 0..31
    const int ty = threadIdx.y;   // 0..7
    const float* xb = x + (size_t)b * MD * T_;
    #pragma unroll
    for (int k = 0; k < 4; k++)
        s[ty + k * 8][tx] = xb[(size_t)(c0 + ty + k * 8) * T_ + t0 + tx];
    __syncthreads();
    const int id = ty * 32 + tx;     // 0..255
    const int tl = id >> 3;          // t_local 0..31
    const int c4 = (id & 7) * 4;     // c_local group
    short4 h4, l4;
    split1h(s[c4 + 0][tl], h4.x, l4.x);
    split1h(s[c4 + 1][tl], h4.y, l4.y);
    split1h(s[c4 + 2][tl], h4.z, l4.z);
    split1h(s[c4 + 3][tl], h4.w, l4.w);
    const size_t o = ((size_t)b * T_ + t0 + tl) * MD + c0 + c4;
    *(short4*)&xTh[o] = h4;
    *(short4*)&xTl[o] = l4;
}

// ---------------------------------------------------------------------------
// Kernel 2: expand GEMM, single-pass fp16 MFMA. 128x128 tile, BK=32, 4 waves
// of 4x4 16x16x32 tiles, global_load_lds 16B. Output y stored as fp16 into
// the FIRST 8KB of each row's 16KB out1 slot (topk reads it, then overwrites
// the full 16KB with sparse f32 -- self-overlap within a row only, race-free).
// ---------------------------------------------------------------------------
__launch_bounds__(256)
__global__ void k_gemm_mfma(const short* __restrict__ xTh,
                            const short* __restrict__ Weh,
                            const float* __restrict__ be,
                            float* __restrict__ y) {
    __shared__ __align__(16) short Ah[128 * 32];
    __shared__ __align__(16) short Bh[128 * 32];

    const int t0  = blockIdx.x * 128;
    const int d0  = blockIdx.y * 128;
    const int b   = blockIdx.z;
    const int tid = threadIdx.x;
    const int lane = tid & 63;
    const int wave = tid >> 6;
    const int wm = wave >> 1, wn = wave & 1;
    const int fm = lane & 15, fq = lane >> 4;

    const short* A_h = Weh + (size_t)d0 * MD;
    const short* B_h = xTh + ((size_t)b * T_ + t0) * MD;

    f32x4 acc[4][4];
    #pragma unroll
    for (int i = 0; i < 4; i++)
        #pragma unroll
        for (int j = 0; j < 4; j++) acc[i][j] = (f32x4)0.f;

    for (int k0 = 0; k0 < MD; k0 += 32) {
        #pragma unroll
        for (int i = 0; i < 2; i++) {
            const int e   = i * 256 + tid;
            const int row = e >> 2, kc = (e & 3) << 3;
            const size_t go = (size_t)row * MD + k0 + kc;
            const int lo = e << 3;   // shorts
            gload_lds16(A_h + go, &Ah[lo]);
            gload_lds16(B_h + go, &Bh[lo]);
        }
        __syncthreads();

        half8 ah[4], bh[4];
        #pragma unroll
        for (int mt = 0; mt < 4; mt++) {
            const int r = wm * 64 + mt * 16 + fm;
            ah[mt] = *(const half8*)&Ah[r * 32 + fq * 8];
        }
        #pragma unroll
        for (int nt = 0; nt < 4; nt++) {
            const int r = wn * 64 + nt * 16 + fm;
            bh[nt] = *(const half8*)&Bh[r * 32 + fq * 8];
        }
        #pragma unroll
        for (int mt = 0; mt < 4; mt++)
            #pragma unroll
            for (int nt = 0; nt < 4; nt++)
                acc[mt][nt] = __builtin_amdgcn_mfma_f32_16x16x32_f16(
                    ah[mt], bh[nt], acc[mt][nt], 0, 0, 0);
        __syncthreads();
    }

    // epilogue: C/D layout col=lane&15 (t), row=fq*4+r (d). fp16 stores.
    _Float16* yh = (_Float16*)y;
    #pragma unroll
    for (int mt = 0; mt < 4; mt++) {
        #pragma unroll
        for (int r = 0; r < 4; r++) {
            const int d = d0 + wm * 64 + mt * 16 + fq * 4 + r;
            const float bias = be[d];
            _Float16* yd = yh + ((size_t)b * HD + d) * (2 * T_)
                              + t0 + wn * 64 + fm;
            #pragma unroll
            for (int nt = 0; nt < 4; nt++)
                yd[nt * 16] = (_Float16)(acc[mt][nt][r] + bias);
        }
    }
}

// ---------------------------------------------------------------------------
// Kernel 3: exact top-64 per row of 4096 (fp16-measured values).
// Statistics threshold (mu+2sd, E[count]~93) -> collect candidates as packed
// u64 keys (value<<32 | ~idx) -> exact 64th V by O(nc) rank with single
// 64-bit compare per step. Band +-BANDW around V: definite keep/drop outside,
// in-band refined: stage 1 = per-wave fp64 dot from f16 hi+lo reconstruction
// (err ~1e-8, no block barriers); stage 2 (iff refined gap < AMB, rare) =
// exact fp64 from f32 inputs. Writes full sparse f32 row over its own fp16.
// ---------------------------------------------------------------------------
__launch_bounds__(256)
__global__ void k_topk(float* __restrict__ y,
                       const float* __restrict__ x,
                       const float* __restrict__ We,
                       const float* __restrict__ be,
                       const short* __restrict__ xTh,
                       const short* __restrict__ xTl,
                       int* __restrict__ colcnt, float2* __restrict__ collist) {
    __shared__ double s_redd[256];              // fp64 scratch (stage 2)
    __shared__ float  s_fred[8];
    __shared__ int    s_ired[8];
    __shared__ unsigned long long s_ck[NCAND];  // (sortable<<32) | ~idx
    __shared__ int s_n;
    __shared__ uint32_t s_Vu;
    __shared__ int s_bidx[64];
    __shared__ double s_bval[64];
    __shared__ unsigned char s_bkeep[64];
    __shared__ int s_nhi, s_nb, s_flag;

    const int row  = blockIdx.x;
    const int b    = row >> 11;
    const int d    = row & 2047;
    const int tid  = threadIdx.x;
    const int lane = tid & 63;
    const int wave = tid >> 6;
    float* yrow = y + (size_t)row * T_;

    // ---- load fp16 row (first 8KB of this row's slot) -> 16 floats ----
    const short* yrow16 = (const short*)yrow;
    short8 r0 = *(const short8*)&yrow16[(size_t)tid * 8];
    short8 r1 = *(const short8*)&yrow16[(size_t)(256 + tid) * 8];
    float fv[16];
    #pragma unroll
    for (int e = 0; e < 8; e++) { fv[e] = h2f(r0[e]); fv[8 + e] = h2f(r1[e]); }
    // element index of fv[q]: q<8 ? tid*8+q : 2048+tid*8+(q-8)

    // ---- row stats (mu, sd) ----
    float s1 = 0.f, s2 = 0.f;
    #pragma unroll
    for (int q = 0; q < 16; q++) { s1 += fv[q]; s2 = fmaf(fv[q], fv[q], s2); }
    for (int off = 32; off > 0; off >>= 1) {
        s1 += __shfl_down(s1, off);
        s2 += __shfl_down(s2, off);
    }
    if (lane == 0) { s_fred[wave] = s1; s_fred[4 + wave] = s2; }
    __syncthreads();
    const float S1 = s_fred[0] + s_fred[1] + s_fred[2] + s_fred[3];
    const float S2 = s_fred[4] + s_fred[5] + s_fred[6] + s_fred[7];
    const float mu = S1 * (1.f / T_);
    const float sd = sqrtf(fmaxf(S2 * (1.f / T_) - mu * mu, 1e-20f));

    // ---- find threshold with KEEP <= count <= NCAND ----
    float thr = mu + 2.0f * sd;
    int total = 0;
    for (int iter = 0; iter < 16; iter++) {
        int c = 0;
        #pragma unroll
        for (int q = 0; q < 16; q++) c += (fv[q] >= thr);
        for (int off = 32; off > 0; off >>= 1) c += __shfl_down(c, off);
        __syncthreads();               // protect s_ired reuse
        if (lane == 0) s_ired[wave] = c;
        __syncthreads();
        total = s_ired[0] + s_ired[1] + s_ired[2] + s_ired[3];
        if (total >= KEEP_ && total <= NCAND) break;
        thr += (total < KEEP_) ? (-0.25f * sd) : (0.25f * sd);
    }

    // ---- collect candidates as packed keys ----
    if (tid == 0) { s_n = 0; s_Vu = 0; }
    __syncthreads();
    #pragma unroll
    for (int q = 0; q < 16; q++) {
        if (fv[q] >= thr) {
            const int i = (q < 8) ? (tid * 8 + q) : (2048 + tid * 8 + (q - 8));
            const int pos = atomicAdd(&s_n, 1);
            if (pos < NCAND)
                s_ck[pos] = ((unsigned long long)sortable(fv[q]) << 32) |
                            (uint32_t)(~i);
        }
    }
    __syncthreads();
    int nc = min(s_n, NCAND);

    // ---- exact rank: find 64th-largest (ties -> lower index wins) ----
    for (int ci = tid; ci < nc; ci += 256) {
        const unsigned long long k = s_ck[ci];
        int r = 0;
        for (int j = 0; j < nc; j++) r += (s_ck[j] > k);
        if (r == KEEP_ - 1) s_Vu = (uint32_t)(k >> 32);
    }
    __syncthreads();
    const uint32_t Vu = s_Vu;
    const uint32_t Vb = (Vu & 0x80000000u) ? (Vu & 0x7FFFFFFFu) : ~Vu;
    const float Vf = __uint_as_float(Vb);
    const float hi_thr = Vf + BANDW;
    const float lo_thr = Vf - BANDW;
    const uint32_t hiU = sortable(hi_thr);
    const uint32_t loU = sortable(lo_thr);

    // ---- ensure band completeness: recollect if lo_thr below threshold ----
    if (lo_thr < thr) {
        __syncthreads();
        if (tid == 0) s_n = 0;
        __syncthreads();
        #pragma unroll
        for (int q = 0; q < 16; q++) {
            if (fv[q] >= lo_thr) {
                const int i = (q < 8) ? (tid * 8 + q)
                                      : (2048 + tid * 8 + (q - 8));
                const int pos = atomicAdd(&s_n, 1);
                if (pos < NCAND)
                    s_ck[pos] = ((unsigned long long)sortable(fv[q]) << 32) |
                                (uint32_t)(~i);
            }
        }
        __syncthreads();
        nc = min(s_n, NCAND);
    }

    // ---- classify candidates: count > hi band, collect in-band ----
    if (tid == 0) { s_nhi = 0; s_nb = 0; }
    __syncthreads();
    for (int ci = tid; ci < nc; ci += 256) {
        const unsigned long long k = s_ck[ci];
        const uint32_t u = (uint32_t)(k >> 32);
        if (u > hiU) {
            atomicAdd(&s_nhi, 1);
        } else if (u >= loU) {
            const int p = atomicAdd(&s_nb, 1);
            if (p < 64) s_bidx[p] = (int)(~(uint32_t)k & 0xFFFFu);
        }
    }
    __syncthreads();
    const int nb    = min(s_nb, 64);
    const int slots = KEEP_ - s_nhi;

    if (nb > slots) {
        // Stage 1: per-wave fp64 refinement from f16 hi+lo reconstruction.
        // Candidate j -> wave j%4; 64 lanes x 16 channels; shuffle reduce.
        const int c0l = lane * 16;
        const float* wrow = We + (size_t)d * MD;
        for (int j = wave; j < nb; j += 4) {
            const int t = s_bidx[j];
            const size_t xo = ((size_t)b * T_ + t) * MD + c0l;
            double acc = 0.0;
            #pragma unroll
            for (int qq = 0; qq < 4; qq++) {
                const float4 w4 = *(const float4*)&wrow[c0l + qq * 4];
                const short4 h4 = *(const short4*)&xTh[xo + qq * 4];
                const short4 l4 = *(const short4*)&xTl[xo + qq * 4];
                acc += (double)w4.x * (double)(h2f(h4.x) + h2f(l4.x));
                acc += (double)w4.y * (double)(h2f(h4.y) + h2f(l4.y));
                acc += (double)w4.z * (double)(h2f(h4.z) + h2f(l4.z));
                acc += (double)w4.w * (double)(h2f(h4.w) + h2f(l4.w));
            }
            #pragma unroll
            for (int off = 32; off > 0; off >>= 1)
                acc += __shfl_down(acc, off);
            if (lane == 0) s_bval[j] = acc + (double)be[d];
        }
        __syncthreads();
        if (tid < nb) {
            const double v = s_bval[tid];
            const int    ti = s_bidx[tid];
            int rank = 0;
            for (int j = 0; j < nb; j++) {
                if (j == tid) continue;
                if (s_bval[j] > v ||
                    (s_bval[j] == v && s_bidx[j] < ti)) rank++;
            }
            s_bkeep[tid] = (rank < slots) ? 1 : 0;
        }
        __syncthreads();
        // ambiguity check: gap between kept-min and dropped-max
        if (tid == 0) {
            double kmin = 1e300, dmax = -1e300;
            for (int j = 0; j < nb; j++) {
                if (s_bkeep[j]) { if (s_bval[j] < kmin) kmin = s_bval[j]; }
                else            { if (s_bval[j] > dmax) dmax = s_bval[j]; }
            }
            s_flag = (kmin - dmax < AMB) ? 1 : 0;
        }
        __syncthreads();
        if (s_flag) {
            // Stage 2 (rare): exact fp64 from original f32 inputs
            for (int j = 0; j < nb; j++) {
                const int t = s_bidx[j];
                double partial = 0.0;
                for (int c = tid; c < MD; c += 256)
                    partial += (double)We[(size_t)d * MD + c] *
                               (double)x[((size_t)b * MD + c) * T_ + t];
                s_redd[tid] = partial;
                __syncthreads();
                for (int off = 128; off > 0; off >>= 1) {
                    if (tid < off) s_redd[tid] += s_redd[tid + off];
                    __syncthreads();
                }
                if (tid == 0) s_bval[j] = s_redd[0] + (double)be[d];
                __syncthreads();
            }
            if (tid < nb) {
                const double v = s_bval[tid];
                const int    ti = s_bidx[tid];
                int rank = 0;
                for (int j = 0; j < nb; j++) {
                    if (j == tid) continue;
                    if (s_bval[j] > v ||
                        (s_bval[j] == v && s_bidx[j] < ti)) rank++;
                }
                s_bkeep[tid] = (rank < slots) ? 1 : 0;
            }
        }
    } else {
        if (tid < nb) s_bkeep[tid] = 1;
    }
    __syncthreads();

    // ---- write back sparse f32 row + scatter kept into column lists ----
    #pragma unroll
    for (int jj = 0; jj < 2; jj++) {
        float buf[8];
        #pragma unroll
        for (int e = 0; e < 8; e++) {
            const int q = jj * 8 + e;
            const int i = jj * 2048 + tid * 8 + e;
            const float f = fv[q];
            const uint32_t u = sortable(f);
            bool keep;
            if (u > hiU) {
                keep = true;
            } else if (u < loU) {
                keep = false;
            } else {
                keep = false;
                for (int p = 0; p < nb; p++)
                    if (s_bidx[p] == i) { keep = (s_bkeep[p] != 0); break; }
            }
            if (keep) {
                const int col = b * T_ + i;
                const int pos = atomicAdd(&colcnt[col], 1);
                if (pos < CAP)
                    collist[(size_t)col * CAP + pos] =
                        make_float2(__int_as_float(d), f);
                buf[e] = f;
            } else {
                buf[e] = 0.0f;
            }
        }
        float* base = yrow + jj * 2048 + (size_t)tid * 8;
        *(float4*)(base)     = make_float4(buf[0], buf[1], buf[2], buf[3]);
        *(float4*)(base + 4) = make_float4(buf[4], buf[5], buf[6], buf[7]);
    }
}

// ---------------------------------------------------------------------------
// Kernel 4 (v2): sparse contract  out[b,m,t] = bc[m] + sum_nnz val * WcT[d][m]
// Each thread owns 4 consecutive m (m4 = tid*4): per nnz ONE uint2 (8B) load
// of WcT[d][m4..m4+3], bf16->f32 via shift/and bit-tricks, 4 fma. Covers all
// 1024 m in one pass (vs 4), ~4x fewer VALU ops and loads than scalar-per-m.
// c processed in groups of 4 (16 f32 accs, named vectors -> registers).
// No LDS transpose: direct float4 stores (4 m-rows x 16 contiguous t).
// ---------------------------------------------------------------------------
__launch_bounds__(256)
__global__ void k_contract(const int* __restrict__ colcnt,
                           const float2* __restrict__ collist,
                           const __hip_bfloat16* __restrict__ WcT,
                           const float* __restrict__ bc,
                           float* __restrict__ out) {
    __shared__ float2 s_list[16][CAP];
    __shared__ int    s_cnt[16];

    const int t0  = blockIdx.x * 16;
    const int b   = blockIdx.y;
    const int tid = threadIdx.x;
    const int m4  = tid * 4;

    if (tid < 16) s_cnt[tid] = min(colcnt[b * T_ + t0 + tid], CAP);
    __syncthreads();
    #pragma unroll
    for (int c = 0; c < 16; c++) {
        const int n = s_cnt[c];
        for (int i = tid; i < n; i += 256)
            s_list[c][i] = collist[(size_t)(b * T_ + t0 + c) * CAP + i];
    }
    __syncthreads();

    const float4 bias4 = *(const float4*)&bc[m4];
    const char* wbase = (const char*)WcT + (size_t)m4 * 2;

    // dot over one column list into a 4-wide (m4..m4+3) accumulator
    auto dot_col = [&](int c, f32x4& a) {
        const int n = s_cnt[c];
        int i = 0;
        for (; i + 2 <= n; i += 2) {
            const float2 e0 = s_list[c][i];
            const float2 e1 = s_list[c][i + 1];
            const uint2 w0 = *(const uint2*)(wbase +
                ((size_t)(uint32_t)__float_as_int(e0.x) << 11));
            const uint2 w1 = *(const uint2*)(wbase +
                ((size_t)(uint32_t)__float_as_int(e1.x) << 11));
            a[0] = fmaf(e0.y, __uint_as_float(w0.x << 16), a[0]);
            a[1] = fmaf(e0.y, __uint_as_float(w0.x & 0xffff0000u), a[1]);
            a[2] = fmaf(e0.y, __uint_as_float(w0.y << 16), a[2]);
            a[3] = fmaf(e0.y, __uint_as_float(w0.y & 0xffff0000u), a[3]);
            a[0] = fmaf(e1.y, __uint_as_float(w1.x << 16), a[0]);
            a[1] = fmaf(e1.y, __uint_as_float(w1.x & 0xffff0000u), a[1]);
            a[2] = fmaf(e1.y, __uint_as_float(w1.y << 16), a[2]);
            a[3] = fmaf(e1.y, __uint_as_float(w1.y & 0xffff0000u), a[3]);
        }
        if (i < n) {
            const float2 e0 = s_list[c][i];
            const uint2 w0 = *(const uint2*)(wbase +
                ((size_t)(uint32_t)__float_as_int(e0.x) << 11));
            a[0] = fmaf(e0.y, __uint_as_float(w0.x << 16), a[0]);
            a[1] = fmaf(e0.y, __uint_as_float(w0.x & 0xffff0000u), a[1]);
            a[2] = fmaf(e0.y, __uint_as_float(w0.y << 16), a[2]);
            a[3] = fmaf(e0.y, __uint_as_float(w0.y & 0xffff0000u), a[3]);
        }
    };

    const f32x4 binit = {bias4.x, bias4.y, bias4.z, bias4.w};

    for (int cg = 0; cg < 4; cg++) {
        f32x4 a0 = binit, a1 = binit, a2 = binit, a3 = binit;
        dot_col(cg * 4 + 0, a0);
        dot_col(cg * 4 + 1, a1);
        dot_col(cg * 4 + 2, a2);
        dot_col(cg * 4 + 3, a3);
        // store: 4 m-rows, 4 consecutive t each (t0 + cg*4 ..)
        #pragma unroll
        for (int j = 0; j < 4; j++) {
            float4 v = make_float4(a0[j], a1[j], a2[j], a3[j]);
            *(float4*)&out[((size_t)b * MD + m4 + j) * T_ + t0 + cg * 4] = v;
        }
    }
}

// ---------------------------------------------------------------------------
extern "C" void kernel_launch(void* const* d_in, const int* in_sizes, int n_in,
                              void* d_out, int out_size, void* d_ws, size_t ws_size,
                              hipStream_t stream) {
    const float* x  = (const float*)d_in[0];   // [B, MD, T]
    const float* We = (const float*)d_in[1];   // [HD, MD]
    const float* be = (const float*)d_in[2];   // [HD]
    const float* Wc = (const float*)d_in[3];   // [MD, HD]
    const float* bc = (const float*)d_in[4];   // [MD]

    float* out0 = (float*)d_out;                        // out    [B, MD, T] (128MB)
    float* out1 = out0 + (size_t)B_ * MD * T_;          // sparse [B, HD, T] (256MB)

    // workspace layout: colcnt (128KB) | collist (24MB) | WcT bf16 (4MB)
    char* ws = (char*)d_ws;
    int*     colcnt  = (int*)ws;
    float2*  collist = (float2*)(ws + (size_t)B_ * T_ * sizeof(int));
    __hip_bfloat16* WcT =
        (__hip_bfloat16*)(ws + (size_t)B_ * T_ * sizeof(int) +
                          (size_t)B_ * T_ * CAP * sizeof(float2));

    // Aliasing (zero extra workspace):
    //  - xT hi/lo (2 x 64MB f16) live in out0's 128MB, overwritten by contract.
    //    (hi feeds gemm; hi+lo feed topk's refinement reconstruction.)
    //  - We f16 (4MB) lives in collist's 24MB, consumed by gemm before topk
    //    writes collist.
    //  - y fp16 lives in the first 8KB of each row's 16KB slot in out1;
    //    topk reads its own row into registers then overwrites with f32.
    short* xTh = (short*)out0;
    short* xTl = xTh + (size_t)B_ * T_ * MD;
    short* Weh = (short*)collist;

    hipMemsetAsync(colcnt, 0, (size_t)B_ * T_ * sizeof(int), stream);

    k_transpose_wc<<<dim3(HD / 32, MD / 32), dim3(32, 8), 0, stream>>>(Wc, WcT);
    k_round_we<<<(HD * MD) / 1024, 256, 0, stream>>>(We, Weh);
    k_split_x<<<dim3(T_ / 32, MD / 32, B_), dim3(32, 8), 0, stream>>>(x, xTh, xTl);
    k_gemm_mfma<<<dim3(T_ / 128, HD / 128, B_), 256, 0, stream>>>(
        xTh, Weh, be, out1);
    k_topk<<<B_ * HD, 256, 0, stream>>>(out1, x, We, be, xTh, xTl,
                                        colcnt, collist);
    k_contract<<<dim3(T_ / 16, B_), 256, 0, stream>>>(colcnt, collist, WcT, bc, out0);
}

// Round 5
// 1084.203 us; speedup vs baseline: 1.1028x; 1.1028x over previous
//
#include <hip/hip_runtime.h>
#include <hip/hip_bf16.h>
#include <stdint.h>

// Problem constants
#define B_    8
#define MD    1024   // MODEL_DIM
#define HD    2048   // HIGH_DIM
#define T_    4096
#define KEEP_ 64
#define CAP   96     // per-column nnz capacity (mean 32; P(>96) ~ 1e-18)
#define BANDW 5e-3f  // band half-width >= 2*(fp16 GEMM err 1.4e-3 + fp16 store err 0.5e-3)
#define AMB   2e-6   // refined-cut ambiguity margin -> exact fp64 fallback
#define NCAND 512    // candidate list capacity for threshold top-k

typedef __attribute__((ext_vector_type(8))) short short8;
typedef __attribute__((ext_vector_type(4))) float f32x4;
typedef __attribute__((ext_vector_type(8))) _Float16 half8;

// async global->LDS, 16B per lane (wave-uniform LDS base + lane*16)
__device__ __forceinline__ void gload_lds16(const void* g, void* l) {
    __builtin_amdgcn_global_load_lds(
        (const __attribute__((address_space(1))) uint32_t*)g,
        (__attribute__((address_space(3))) uint32_t*)l, 16, 0, 0);
}

__device__ __forceinline__ short f2h(float a) {
    _Float16 h = (_Float16)a;
    short s;
    __builtin_memcpy(&s, &h, 2);
    return s;
}

__device__ __forceinline__ float h2f(short s) {
    _Float16 h;
    __builtin_memcpy(&h, &s, 2);
    return (float)h;
}

// split f32 into fp16 hi + fp16 lo (hi+lo reconstructs to ~2^-22 relative)
__device__ __forceinline__ void split1h(float a, short& h, short& l) {
    _Float16 hh = (_Float16)a;
    float r = a - (float)hh;   // exact (Sterbenz)
    h = f2h(a);
    l = f2h(r);
    (void)hh;
}

__device__ __forceinline__ uint32_t sortable(float f) {
    uint32_t u = __float_as_uint(f);
    return (u & 0x80000000u) ? ~u : (u | 0x80000000u);
}

// ---------------------------------------------------------------------------
// Kernel 1: transpose W_c [MD][HD] f32 -> W_cT [HD][MD] bf16 (L2-resident 4MB)
// ---------------------------------------------------------------------------
__global__ void k_transpose_wc(const float* __restrict__ Wc,
                               __hip_bfloat16* __restrict__ WcT) {
    __shared__ float s[32][33];
    const int d0 = blockIdx.x * 32;
    const int m0 = blockIdx.y * 32;
    const int tx = threadIdx.x;   // 0..31
    const int ty = threadIdx.y;   // 0..7
    #pragma unroll
    for (int k = 0; k < 4; k++)
        s[ty + k * 8][tx] = Wc[(size_t)(m0 + ty + k * 8) * HD + d0 + tx];
    __syncthreads();
    #pragma unroll
    for (int k = 0; k < 4; k++)
        WcT[(size_t)(d0 + ty + k * 8) * MD + m0 + tx] =
            __float2bfloat16(s[tx][ty + k * 8]);
}

// ---------------------------------------------------------------------------
// Kernel 1b: round We [HD][MD] f32 -> fp16 (elementwise; single array)
// ---------------------------------------------------------------------------
__global__ void k_round_we(const float* __restrict__ We,
                           short* __restrict__ hi) {
    const int i = (blockIdx.x * 256 + threadIdx.x) * 4;
    float4 v = *(const float4*)&We[i];
    short4 h;
    h.x = f2h(v.x);
    h.y = f2h(v.y);
    h.z = f2h(v.z);
    h.w = f2h(v.w);
    *(short4*)&hi[i] = h;
}

// ---------------------------------------------------------------------------
// Kernel 1c: transpose+split x [B][MD][T] f32 -> xT hi/lo [B][T][MD] fp16.
// hi feeds the 1-pass GEMM; hi+lo reconstruct x to 2^-22 for refinement.
// ---------------------------------------------------------------------------
__global__ void k_split_x(const float* __restrict__ x,
                          short* __restrict__ xTh, short* __restrict__ xTl) {
    __shared__ float s[32][33];   // [c_local][t_local]
    const int t0 = blockIdx.x * 32;
    const int c0 = blockIdx.y * 32;
    const int b  = blockIdx.z;
    const int tx = threadIdx.x;   // 0..31
    const int ty = threadIdx.y;   // 0..7
    const float* xb = x + (size_t)b * MD * T_;
    #pragma unroll
    for (int k = 0; k < 4; k++)
        s[ty + k * 8][tx] = xb[(size_t)(c0 + ty + k * 8) * T_ + t0 + tx];
    __syncthreads();
    const int id = ty * 32 + tx;     // 0..255
    const int tl = id >> 3;          // t_local 0..31
    const int c4 = (id & 7) * 4;     // c_local group
    short4 h4, l4;
    split1h(s[c4 + 0][tl], h4.x, l4.x);
    split1h(s[c4 + 1][tl], h4.y, l4.y);
    split1h(s[c4 + 2][tl], h4.z, l4.z);
    split1h(s[c4 + 3][tl], h4.w, l4.w);
    const size_t o = ((size_t)b * T_ + t0 + tl) * MD + c0 + c4;
    *(short4*)&xTh[o] = h4;
    *(short4*)&xTl[o] = l4;
}

// ---------------------------------------------------------------------------
// Kernel 2: expand GEMM, single-pass fp16 MFMA. 128x128 tile, BK=32, 4 waves
// of 4x4 16x16x32 tiles, global_load_lds 16B. Output y stored as fp16 into
// the FIRST 8KB of each row's 16KB out1 slot (topk reads it, then overwrites
// the full 16KB with sparse f32 -- self-overlap within a row only, race-free).
// ---------------------------------------------------------------------------
__launch_bounds__(256)
__global__ void k_gemm_mfma(const short* __restrict__ xTh,
                            const short* __restrict__ Weh,
                            const float* __restrict__ be,
                            float* __restrict__ y) {
    __shared__ __align__(16) short Ah[128 * 32];
    __shared__ __align__(16) short Bh[128 * 32];

    const int t0  = blockIdx.x * 128;
    const int d0  = blockIdx.y * 128;
    const int b   = blockIdx.z;
    const int tid = threadIdx.x;
    const int lane = tid & 63;
    const int wave = tid >> 6;
    const int wm = wave >> 1, wn = wave & 1;
    const int fm = lane & 15, fq = lane >> 4;

    const short* A_h = Weh + (size_t)d0 * MD;
    const short* B_h = xTh + ((size_t)b * T_ + t0) * MD;

    f32x4 acc[4][4];
    #pragma unroll
    for (int i = 0; i < 4; i++)
        #pragma unroll
        for (int j = 0; j < 4; j++) acc[i][j] = (f32x4)0.f;

    for (int k0 = 0; k0 < MD; k0 += 32) {
        #pragma unroll
        for (int i = 0; i < 2; i++) {
            const int e   = i * 256 + tid;
            const int row = e >> 2, kc = (e & 3) << 3;
            const size_t go = (size_t)row * MD + k0 + kc;
            const int lo = e << 3;   // shorts
            gload_lds16(A_h + go, &Ah[lo]);
            gload_lds16(B_h + go, &Bh[lo]);
        }
        __syncthreads();

        half8 ah[4], bh[4];
        #pragma unroll
        for (int mt = 0; mt < 4; mt++) {
            const int r = wm * 64 + mt * 16 + fm;
            ah[mt] = *(const half8*)&Ah[r * 32 + fq * 8];
        }
        #pragma unroll
        for (int nt = 0; nt < 4; nt++) {
            const int r = wn * 64 + nt * 16 + fm;
            bh[nt] = *(const half8*)&Bh[r * 32 + fq * 8];
        }
        #pragma unroll
        for (int mt = 0; mt < 4; mt++)
            #pragma unroll
            for (int nt = 0; nt < 4; nt++)
                acc[mt][nt] = __builtin_amdgcn_mfma_f32_16x16x32_f16(
                    ah[mt], bh[nt], acc[mt][nt], 0, 0, 0);
        __syncthreads();
    }

    // epilogue: C/D layout col=lane&15 (t), row=fq*4+r (d). fp16 stores.
    _Float16* yh = (_Float16*)y;
    #pragma unroll
    for (int mt = 0; mt < 4; mt++) {
        #pragma unroll
        for (int r = 0; r < 4; r++) {
            const int d = d0 + wm * 64 + mt * 16 + fq * 4 + r;
            const float bias = be[d];
            _Float16* yd = yh + ((size_t)b * HD + d) * (2 * T_)
                              + t0 + wn * 64 + fm;
            #pragma unroll
            for (int nt = 0; nt < 4; nt++)
                yd[nt * 16] = (_Float16)(acc[mt][nt][r] + bias);
        }
    }
}

// ---------------------------------------------------------------------------
// Kernel 3: exact top-64 per row of 4096 (fp16-measured values).
// Statistics threshold (mu+2sd, E[count]~93) -> collect candidates as packed
// u64 keys (value<<32 | ~idx) -> exact 64th V by O(nc) rank with single
// 64-bit compare per step. Band +-BANDW around V: definite keep/drop outside,
// in-band refined: stage 1 = per-wave fp64 dot from f16 hi+lo reconstruction
// (err ~1e-8, no block barriers); stage 2 (iff refined gap < AMB, rare) =
// exact fp64 from f32 inputs. Writes full sparse f32 row over its own fp16
// with NONTEMPORAL stores (never re-read; keeps L2 for y16 + WcT).
// ---------------------------------------------------------------------------
__launch_bounds__(256)
__global__ void k_topk(float* __restrict__ y,
                       const float* __restrict__ x,
                       const float* __restrict__ We,
                       const float* __restrict__ be,
                       const short* __restrict__ xTh,
                       const short* __restrict__ xTl,
                       int* __restrict__ colcnt, float2* __restrict__ collist) {
    __shared__ double s_redd[256];              // fp64 scratch (stage 2)
    __shared__ float  s_fred[8];
    __shared__ int    s_ired[8];
    __shared__ unsigned long long s_ck[NCAND];  // (sortable<<32) | ~idx
    __shared__ int s_n;
    __shared__ uint32_t s_Vu;
    __shared__ int s_bidx[64];
    __shared__ double s_bval[64];
    __shared__ unsigned char s_bkeep[64];
    __shared__ int s_nhi, s_nb, s_flag;

    const int row  = blockIdx.x;
    const int b    = row >> 11;
    const int d    = row & 2047;
    const int tid  = threadIdx.x;
    const int lane = tid & 63;
    const int wave = tid >> 6;
    float* yrow = y + (size_t)row * T_;

    // ---- load fp16 row (first 8KB of this row's slot) -> 16 floats ----
    const short* yrow16 = (const short*)yrow;
    short8 r0 = *(const short8*)&yrow16[(size_t)tid * 8];
    short8 r1 = *(const short8*)&yrow16[(size_t)(256 + tid) * 8];
    float fv[16];
    #pragma unroll
    for (int e = 0; e < 8; e++) { fv[e] = h2f(r0[e]); fv[8 + e] = h2f(r1[e]); }
    // element index of fv[q]: q<8 ? tid*8+q : 2048+tid*8+(q-8)

    // ---- row stats (mu, sd) ----
    float s1 = 0.f, s2 = 0.f;
    #pragma unroll
    for (int q = 0; q < 16; q++) { s1 += fv[q]; s2 = fmaf(fv[q], fv[q], s2); }
    for (int off = 32; off > 0; off >>= 1) {
        s1 += __shfl_down(s1, off);
        s2 += __shfl_down(s2, off);
    }
    if (lane == 0) { s_fred[wave] = s1; s_fred[4 + wave] = s2; }
    __syncthreads();
    const float S1 = s_fred[0] + s_fred[1] + s_fred[2] + s_fred[3];
    const float S2 = s_fred[4] + s_fred[5] + s_fred[6] + s_fred[7];
    const float mu = S1 * (1.f / T_);
    const float sd = sqrtf(fmaxf(S2 * (1.f / T_) - mu * mu, 1e-20f));

    // ---- find threshold with KEEP <= count <= NCAND ----
    float thr = mu + 2.0f * sd;
    int total = 0;
    for (int iter = 0; iter < 16; iter++) {
        int c = 0;
        #pragma unroll
        for (int q = 0; q < 16; q++) c += (fv[q] >= thr);
        for (int off = 32; off > 0; off >>= 1) c += __shfl_down(c, off);
        __syncthreads();               // protect s_ired reuse
        if (lane == 0) s_ired[wave] = c;
        __syncthreads();
        total = s_ired[0] + s_ired[1] + s_ired[2] + s_ired[3];
        if (total >= KEEP_ && total <= NCAND) break;
        thr += (total < KEEP_) ? (-0.25f * sd) : (0.25f * sd);
    }

    // ---- collect candidates as packed keys ----
    if (tid == 0) { s_n = 0; s_Vu = 0; }
    __syncthreads();
    #pragma unroll
    for (int q = 0; q < 16; q++) {
        if (fv[q] >= thr) {
            const int i = (q < 8) ? (tid * 8 + q) : (2048 + tid * 8 + (q - 8));
            const int pos = atomicAdd(&s_n, 1);
            if (pos < NCAND)
                s_ck[pos] = ((unsigned long long)sortable(fv[q]) << 32) |
                            (uint32_t)(~i);
        }
    }
    __syncthreads();
    int nc = min(s_n, NCAND);

    // ---- exact rank: find 64th-largest (ties -> lower index wins) ----
    for (int ci = tid; ci < nc; ci += 256) {
        const unsigned long long k = s_ck[ci];
        int r = 0;
        for (int j = 0; j < nc; j++) r += (s_ck[j] > k);
        if (r == KEEP_ - 1) s_Vu = (uint32_t)(k >> 32);
    }
    __syncthreads();
    const uint32_t Vu = s_Vu;
    const uint32_t Vb = (Vu & 0x80000000u) ? (Vu & 0x7FFFFFFFu) : ~Vu;
    const float Vf = __uint_as_float(Vb);
    const float hi_thr = Vf + BANDW;
    const float lo_thr = Vf - BANDW;
    const uint32_t hiU = sortable(hi_thr);
    const uint32_t loU = sortable(lo_thr);

    // ---- ensure band completeness: recollect if lo_thr below threshold ----
    if (lo_thr < thr) {
        __syncthreads();
        if (tid == 0) s_n = 0;
        __syncthreads();
        #pragma unroll
        for (int q = 0; q < 16; q++) {
            if (fv[q] >= lo_thr) {
                const int i = (q < 8) ? (tid * 8 + q)
                                      : (2048 + tid * 8 + (q - 8));
                const int pos = atomicAdd(&s_n, 1);
                if (pos < NCAND)
                    s_ck[pos] = ((unsigned long long)sortable(fv[q]) << 32) |
                                (uint32_t)(~i);
            }
        }
        __syncthreads();
        nc = min(s_n, NCAND);
    }

    // ---- classify candidates: count > hi band, collect in-band ----
    if (tid == 0) { s_nhi = 0; s_nb = 0; }
    __syncthreads();
    for (int ci = tid; ci < nc; ci += 256) {
        const unsigned long long k = s_ck[ci];
        const uint32_t u = (uint32_t)(k >> 32);
        if (u > hiU) {
            atomicAdd(&s_nhi, 1);
        } else if (u >= loU) {
            const int p = atomicAdd(&s_nb, 1);
            if (p < 64) s_bidx[p] = (int)(~(uint32_t)k & 0xFFFFu);
        }
    }
    __syncthreads();
    const int nb    = min(s_nb, 64);
    const int slots = KEEP_ - s_nhi;

    if (nb > slots) {
        // Stage 1: per-wave fp64 refinement from f16 hi+lo reconstruction.
        // Candidate j -> wave j%4; 64 lanes x 16 channels; shuffle reduce.
        const int c0l = lane * 16;
        const float* wrow = We + (size_t)d * MD;
        for (int j = wave; j < nb; j += 4) {
            const int t = s_bidx[j];
            const size_t xo = ((size_t)b * T_ + t) * MD + c0l;
            double acc = 0.0;
            #pragma unroll
            for (int qq = 0; qq < 4; qq++) {
                const float4 w4 = *(const float4*)&wrow[c0l + qq * 4];
                const short4 h4 = *(const short4*)&xTh[xo + qq * 4];
                const short4 l4 = *(const short4*)&xTl[xo + qq * 4];
                acc += (double)w4.x * (double)(h2f(h4.x) + h2f(l4.x));
                acc += (double)w4.y * (double)(h2f(h4.y) + h2f(l4.y));
                acc += (double)w4.z * (double)(h2f(h4.z) + h2f(l4.z));
                acc += (double)w4.w * (double)(h2f(h4.w) + h2f(l4.w));
            }
            #pragma unroll
            for (int off = 32; off > 0; off >>= 1)
                acc += __shfl_down(acc, off);
            if (lane == 0) s_bval[j] = acc + (double)be[d];
        }
        __syncthreads();
        if (tid < nb) {
            const double v = s_bval[tid];
            const int    ti = s_bidx[tid];
            int rank = 0;
            for (int j = 0; j < nb; j++) {
                if (j == tid) continue;
                if (s_bval[j] > v ||
                    (s_bval[j] == v && s_bidx[j] < ti)) rank++;
            }
            s_bkeep[tid] = (rank < slots) ? 1 : 0;
        }
        __syncthreads();
        // ambiguity check: gap between kept-min and dropped-max
        if (tid == 0) {
            double kmin = 1e300, dmax = -1e300;
            for (int j = 0; j < nb; j++) {
                if (s_bkeep[j]) { if (s_bval[j] < kmin) kmin = s_bval[j]; }
                else            { if (s_bval[j] > dmax) dmax = s_bval[j]; }
            }
            s_flag = (kmin - dmax < AMB) ? 1 : 0;
        }
        __syncthreads();
        if (s_flag) {
            // Stage 2 (rare): exact fp64 from original f32 inputs
            for (int j = 0; j < nb; j++) {
                const int t = s_bidx[j];
                double partial = 0.0;
                for (int c = tid; c < MD; c += 256)
                    partial += (double)We[(size_t)d * MD + c] *
                               (double)x[((size_t)b * MD + c) * T_ + t];
                s_redd[tid] = partial;
                __syncthreads();
                for (int off = 128; off > 0; off >>= 1) {
                    if (tid < off) s_redd[tid] += s_redd[tid + off];
                    __syncthreads();
                }
                if (tid == 0) s_bval[j] = s_redd[0] + (double)be[d];
                __syncthreads();
            }
            if (tid < nb) {
                const double v = s_bval[tid];
                const int    ti = s_bidx[tid];
                int rank = 0;
                for (int j = 0; j < nb; j++) {
                    if (j == tid) continue;
                    if (s_bval[j] > v ||
                        (s_bval[j] == v && s_bidx[j] < ti)) rank++;
                }
                s_bkeep[tid] = (rank < slots) ? 1 : 0;
            }
        }
    } else {
        if (tid < nb) s_bkeep[tid] = 1;
    }
    __syncthreads();

    // ---- write back sparse f32 row (nontemporal) + scatter into col lists --
    #pragma unroll
    for (int jj = 0; jj < 2; jj++) {
        float buf[8];
        #pragma unroll
        for (int e = 0; e < 8; e++) {
            const int q = jj * 8 + e;
            const int i = jj * 2048 + tid * 8 + e;
            const float f = fv[q];
            const uint32_t u = sortable(f);
            bool keep;
            if (u > hiU) {
                keep = true;
            } else if (u < loU) {
                keep = false;
            } else {
                keep = false;
                for (int p = 0; p < nb; p++)
                    if (s_bidx[p] == i) { keep = (s_bkeep[p] != 0); break; }
            }
            if (keep) {
                const int col = b * T_ + i;
                const int pos = atomicAdd(&colcnt[col], 1);
                if (pos < CAP)
                    collist[(size_t)col * CAP + pos] =
                        make_float2(__int_as_float(d), f);
                buf[e] = f;
            } else {
                buf[e] = 0.0f;
            }
        }
        float* base = yrow + jj * 2048 + (size_t)tid * 8;
        f32x4 v0 = {buf[0], buf[1], buf[2], buf[3]};
        f32x4 v1 = {buf[4], buf[5], buf[6], buf[7]};
        __builtin_nontemporal_store(v0, (f32x4*)base);
        __builtin_nontemporal_store(v1, (f32x4*)(base + 4));
    }
}

// ---------------------------------------------------------------------------
// Kernel 4 (v4): sparse contract  out[b,m,t] = bc[m] + sum_nnz val * WcT[d][m]
// Combines v2's proven coalesced LDS-transpose store (131MB write, WcT stays
// L2-resident) with v3's vectorized gather: thread owns 2 consecutive m, ONE
// uint (4B) load per nnz = 2 bf16 weights -> 2 shift/and + 2 fma (~7 VALU per
// nnz*2m, ~3.5x less than scalar). Wave gather = 256B contiguous per nnz.
// 2 m-chunks of 512; store via s_t[256][17] in 2 parity half-passes each,
// replicating the old instruction-level 64B-segment store pattern exactly.
// ---------------------------------------------------------------------------
__launch_bounds__(256)
__global__ void k_contract(const int* __restrict__ colcnt,
                           const float2* __restrict__ collist,
                           const __hip_bfloat16* __restrict__ WcT,
                           const float* __restrict__ bc,
                           float* __restrict__ out) {
    __shared__ float2 s_list[16][CAP];
    __shared__ int    s_cnt[16];
    __shared__ float  s_t[256][17];

    const int t0  = blockIdx.x * 16;
    const int b   = blockIdx.y;
    const int tid = threadIdx.x;

    if (tid < 16) s_cnt[tid] = min(colcnt[b * T_ + t0 + tid], CAP);
    __syncthreads();
    for (int c = 0; c < 16; c++) {
        const int n = s_cnt[c];
        for (int i = tid; i < n; i += 256)
            s_list[c][i] = collist[(size_t)(b * T_ + t0 + c) * CAP + i];
    }
    __syncthreads();

    for (int mc = 0; mc < 2; mc++) {
        const int m2 = mc * 512 + tid * 2;            // 2 consecutive m
        const char* wb = (const char*)WcT + (size_t)m2 * 2;
        const float bA = bc[m2], bB = bc[m2 + 1];
        float accA[16], accB[16];
        #pragma unroll
        for (int c = 0; c < 16; c++) { accA[c] = bA; accB[c] = bB; }

        #pragma unroll
        for (int c = 0; c < 16; c++) {
            const int n = s_cnt[c];
            int i = 0;
            for (; i + 2 <= n; i += 2) {
                const float2 e0 = s_list[c][i];
                const float2 e1 = s_list[c][i + 1];
                const uint32_t w0 = *(const uint32_t*)(wb +
                    ((size_t)(uint32_t)__float_as_int(e0.x) << 11));
                const uint32_t w1 = *(const uint32_t*)(wb +
                    ((size_t)(uint32_t)__float_as_int(e1.x) << 11));
                accA[c] = fmaf(e0.y, __uint_as_float(w0 << 16), accA[c]);
                accB[c] = fmaf(e0.y, __uint_as_float(w0 & 0xffff0000u), accB[c]);
                accA[c] = fmaf(e1.y, __uint_as_float(w1 << 16), accA[c]);
                accB[c] = fmaf(e1.y, __uint_as_float(w1 & 0xffff0000u), accB[c]);
            }
            if (i < n) {
                const float2 e0 = s_list[c][i];
                const uint32_t w0 = *(const uint32_t*)(wb +
                    ((size_t)(uint32_t)__float_as_int(e0.x) << 11));
                accA[c] = fmaf(e0.y, __uint_as_float(w0 << 16), accA[c]);
                accB[c] = fmaf(e0.y, __uint_as_float(w0 & 0xffff0000u), accB[c]);
            }
        }

        // store: 2 parity half-passes through the proven LDS transpose
        #pragma unroll
        for (int h = 0; h < 2; h++) {
            __syncthreads();          // protect s_t reuse
            #pragma unroll
            for (int c = 0; c < 16; c++)
                s_t[tid][c] = h ? accB[c] : accA[c];
            __syncthreads();
            #pragma unroll
            for (int pass = 0; pass < 4; pass++) {
                const int r  = pass * 64 + (tid >> 2);
                const int cj = (tid & 3) * 4;
                float4 v;
                v.x = s_t[r][cj + 0];
                v.y = s_t[r][cj + 1];
                v.z = s_t[r][cj + 2];
                v.w = s_t[r][cj + 3];
                const int m_out = mc * 512 + r * 2 + h;
                *(float4*)&out[((size_t)b * MD + m_out) * T_ + t0 + cj] = v;
            }
        }
    }
}

// ---------------------------------------------------------------------------
extern "C" void kernel_launch(void* const* d_in, const int* in_sizes, int n_in,
                              void* d_out, int out_size, void* d_ws, size_t ws_size,
                              hipStream_t stream) {
    const float* x  = (const float*)d_in[0];   // [B, MD, T]
    const float* We = (const float*)d_in[1];   // [HD, MD]
    const float* be = (const float*)d_in[2];   // [HD]
    const float* Wc = (const float*)d_in[3];   // [MD, HD]
    const float* bc = (const float*)d_in[4];   // [MD]

    float* out0 = (float*)d_out;                        // out    [B, MD, T] (128MB)
    float* out1 = out0 + (size_t)B_ * MD * T_;          // sparse [B, HD, T] (256MB)

    // workspace layout: colcnt (128KB) | collist (24MB) | WcT bf16 (4MB)
    char* ws = (char*)d_ws;
    int*     colcnt  = (int*)ws;
    float2*  collist = (float2*)(ws + (size_t)B_ * T_ * sizeof(int));
    __hip_bfloat16* WcT =
        (__hip_bfloat16*)(ws + (size_t)B_ * T_ * sizeof(int) +
                          (size_t)B_ * T_ * CAP * sizeof(float2));

    // Aliasing (zero extra workspace):
    //  - xT hi/lo (2 x 64MB f16) live in out0's 128MB, overwritten by contract.
    //    (hi feeds gemm; hi+lo feed topk's refinement reconstruction.)
    //  - We f16 (4MB) lives in collist's 24MB, consumed by gemm before topk
    //    writes collist.
    //  - y fp16 lives in the first 8KB of each row's 16KB slot in out1;
    //    topk reads its own row into registers then overwrites with f32.
    short* xTh = (short*)out0;
    short* xTl = xTh + (size_t)B_ * T_ * MD;
    short* Weh = (short*)collist;

    hipMemsetAsync(colcnt, 0, (size_t)B_ * T_ * sizeof(int), stream);

    k_transpose_wc<<<dim3(HD / 32, MD / 32), dim3(32, 8), 0, stream>>>(Wc, WcT);
    k_round_we<<<(HD * MD) / 1024, 256, 0, stream>>>(We, Weh);
    k_split_x<<<dim3(T_ / 32, MD / 32, B_), dim3(32, 8), 0, stream>>>(x, xTh, xTl);
    k_gemm_mfma<<<dim3(T_ / 128, HD / 128, B_), 256, 0, stream>>>(
        xTh, Weh, be, out1);
    k_topk<<<B_ * HD, 256, 0, stream>>>(out1, x, We, be, xTh, xTl,
                                        colcnt, collist);
    k_contract<<<dim3(T_ / 16, B_), 256, 0, stream>>>(colcnt, collist, WcT, bc, out0);
}